// Round 11
// baseline (298.796 us; speedup 1.0000x reference)
//
#include <hip/hip_runtime.h>
#include <cmath>

#define CC 21
#define HH 512
#define WW 512
#define HWSZ (HH*WW)
#define CHW (CC*HWSZ)
#define NITERS 5
#define ROWF (CC*WW)          // 10752 elems per image row in HWC
#define HROWF (CC*256)        // 5376 elems per half row
#define TSTRIDE 272           // tile row stride (interior 16B-aligned at j=8)

struct K9 { float k[9]; };

__device__ __forceinline__ float bf16_to_f(unsigned short v) {
    union { unsigned int i; float f; } cv; cv.i = ((unsigned int)v) << 16; return cv.f;
}
__device__ __forceinline__ unsigned short f_to_bf16(float f) {
    union { float f; unsigned int i; } cv; cv.f = f;
    unsigned int b = cv.i + 0x7FFFu + ((cv.i >> 16) & 1u);   // RNE
    return (unsigned short)(b >> 16);
}
__device__ __forceinline__ float lo_bf(unsigned int u) {
    union { unsigned int i; float f; } cv; cv.i = u << 16; return cv.f;
}
__device__ __forceinline__ float hi_bf(unsigned int u) {
    union { unsigned int i; float f; } cv; cv.i = u & 0xFFFF0000u; return cv.f;
}
__device__ __forceinline__ unsigned int pack2_bf(float a, float b) {
    return (unsigned int)f_to_bf16(a) | ((unsigned int)f_to_bf16(b) << 16);
}

// one-time: unaries (HWC fp32) -> bf16
__global__ void convert_u16_kernel(const float* __restrict__ u, unsigned short* __restrict__ u16) {
    size_t i = ((size_t)blockIdx.x*256 + threadIdx.x) * 4;
    float4 f = *(const float4*)(u + i);
    ushort4 o;
    o.x = f_to_bf16(f.x); o.y = f_to_bf16(f.y);
    o.z = f_to_bf16(f.z); o.w = f_to_bf16(f.w);
    *(ushort4*)(u16 + i) = o;
}

// spT[h*W + w] = sp_map[w*W + h]
__global__ void transpose_sp_kernel(const int* __restrict__ sp, int* __restrict__ spT) {
    int p = blockIdx.x*256 + threadIdx.x;
    int h = p >> 9, w = p & (WW - 1);
    spT[p] = sp[w*WW + h];
}

// M = CM @ (SKW + BKW)
__global__ void precomp_M_kernel(const float* __restrict__ skw, const float* __restrict__ bkw,
                                 const float* __restrict__ cm, float* __restrict__ M) {
    int i = blockIdx.x * blockDim.x + threadIdx.x;
    if (i >= CC*CC) return;
    int r = i / CC, k = i - r*CC;
    float a = 0.f;
    for (int j = 0; j < CC; ++j) a += cm[r*CC + j] * (skw[j*CC + k] + bkw[j*CC + k]);
    M[i] = a;
}

// iter-0: sm0 = softmax(u) -> sm16 (+ fp32 smf & redacc atomics at clique-0 px)
__launch_bounds__(256)
__global__ void init_sm_kernel(const float* __restrict__ unaries,
                               unsigned short* __restrict__ sm16,
                               float* __restrict__ smf,
                               const int* __restrict__ spT,
                               const int* __restrict__ sp_indices,
                               float* __restrict__ redacc) {
    __shared__ __align__(16) float lu[HROWF];
    __shared__ float acc[44];
    __shared__ int anyC;
    int bid = blockIdx.x;
    int h = bid >> 1, w0 = (bid & 1) << 8;
    int tx = threadIdx.x;
    if (tx < 44) acc[tx] = 0.f;
    if (tx == 0) anyC = 0;
    {
        const float4* src = (const float4*)(unaries + (size_t)h*ROWF + w0*CC);
        float4* dst = (float4*)lu;
        #pragma unroll
        for (int j = 0; j < 6; ++j) {
            int idx = j*256 + tx;
            if (idx < HROWF/4) dst[idx] = src[idx];
        }
    }
    __syncthreads();
    int p = h*WW + w0 + tx;
    float v[CC]; float m = -1e30f;
    #pragma unroll
    for (int c = 0; c < CC; ++c) { v[c] = lu[tx*CC + c]; m = fmaxf(m, v[c]); }
    float s = 0.f;
    #pragma unroll
    for (int c = 0; c < CC; ++c) { v[c] = expf(v[c] - m); s += v[c]; }
    float inv = 1.f / s;
    #pragma unroll
    for (int c = 0; c < CC; ++c) { v[c] *= inv; sm16[(size_t)c*HWSZ + p] = f_to_bf16(v[c]); }

    int idx = sp_indices[0];
    int lab = spT[p];
    if (lab == idx || lab == idx + 1) {
        int mk = (lab == idx) ? 0 : 1;
        anyC = 1;
        atomicAdd(&acc[42 + mk], 1.f);
        for (int c = 0; c < CC; ++c) {
            smf[(size_t)c*HWSZ + p] = v[c];
            atomicAdd(&acc[mk*21 + c], expf(v[c]));
        }
    }
    __syncthreads();
    if (anyC && tx < 44) atomicAdd(&redacc[tx], acc[tx]);
}

// single tiny block: B from redacc, then zero redacc for the next iteration.
__launch_bounds__(64)
__global__ void finalize_kernel(float* __restrict__ redacc, float* __restrict__ B) {
    int t = threadIdx.x;
    float s = 0.f, n = 0.f;
    if (t < 42) { s = redacc[t]; n = redacc[42 + t/21]; }
    __syncthreads();
    if (t < 42) B[t] = logf((float)HWSZ - n + s);
    if (t < 44) redacc[t] = 0.f;
}

// vertical 9-tap blur on bf16, zero pad; 8 pixels/thread (uint4 = 8 bf16).
__launch_bounds__(256)
__global__ void vblur_kernel(const unsigned short* __restrict__ sm16,
                             unsigned short* __restrict__ tmp16, K9 kk) {
    size_t idx = ((size_t)blockIdx.x*256 + threadIdx.x) * 8;
    int p = (int)(idx & (HWSZ - 1));
    int h = p >> 9;
    float a0=0,a1=0,a2=0,a3=0,a4=0,a5=0,a6=0,a7=0;
    const unsigned short* base = sm16 + idx;
    #pragma unroll
    for (int t = 0; t < 9; ++t) {
        int hh = h + t - 4;
        if (hh >= 0 && hh < HH) {
            uint4 v = *(const uint4*)(base + (t - 4)*WW);
            float kt = kk.k[t];
            a0 += kt*lo_bf(v.x); a1 += kt*hi_bf(v.x);
            a2 += kt*lo_bf(v.y); a3 += kt*hi_bf(v.y);
            a4 += kt*lo_bf(v.z); a5 += kt*hi_bf(v.z);
            a6 += kt*lo_bf(v.w); a7 += kt*hi_bf(v.w);
        }
    }
    uint4 o;
    o.x = pack2_bf(a0,a1); o.y = pack2_bf(a2,a3);
    o.z = pack2_bf(a4,a5); o.w = pack2_bf(a6,a7);
    *(uint4*)(tmp16 + idx) = o;
}

// Fused: hblur (bf16 LDS tile, uint4-staged) -> /norm -> unrolled M-mix
// (branch-free; clique fixup after) -> softmax (b[] reuse) -> sm16 in-place
// + sparse smf/redacc for next clique. Last iter: HWC gather store.
__launch_bounds__(256)
__global__ void final_kernel(const unsigned short* __restrict__ tmp16,
                             unsigned short* __restrict__ sm16,
                             float* __restrict__ smf,
                             float* __restrict__ outHWC,
                             const unsigned short* __restrict__ u16,
                             const int* __restrict__ spT,
                             const int* __restrict__ sp_indices, int iter,
                             const float* __restrict__ Mg, const float* __restrict__ Bg,
                             const float* __restrict__ lwg, const float* __restrict__ hwg,
                             K9 kk, float* __restrict__ redacc, int last) {
    __shared__ __align__(16) float qlds[HROWF];            // 21504 B
    __shared__ __align__(16) unsigned short lu16[HROWF];   // 10752 B
    __shared__ float acc[44];
    __shared__ int anyC;
    unsigned short* tile16 = (unsigned short*)qlds;        // [CC][TSTRIDE] = 11424 B alias

    int bid = blockIdx.x;                        // 0..1023
    int xcd = bid & 7, tt = bid >> 3;
    int h  = xcd*64 + (tt >> 1);
    int w0 = (tt & 1) << 8;
    int tx = threadIdx.x;
    if (tx < 44) acc[tx] = 0.f;
    if (tx == 0) anyC = 0;

    // stage haloed bf16 tmp tile: interior as uint4 (8 bf16), 21x32 quads
    {
        const unsigned short* trow = tmp16 + (size_t)h*WW + w0;
        #pragma unroll
        for (int i = 0; i < 3; ++i) {
            int task = i*256 + tx;
            if (task < 21*32) {
                int c = task >> 5, q = task & 31;
                uint4 v = *(const uint4*)(trow + (size_t)c*HWSZ + q*8);
                *(uint4*)(tile16 + c*TSTRIDE + 8 + q*8) = v;
            }
        }
        // halo: 8 per row (4 left, 4 right), 168 tasks
        if (tx < 168) {
            int c = tx / 8, k8 = tx - (tx/8)*8;
            int j = (k8 < 4) ? (4 + k8) : (264 + (k8 - 4));
            int gw = w0 + j - 8;
            tile16[c*TSTRIDE + j] = (gw >= 0 && gw < WW)
                ? tmp16[(size_t)c*HWSZ + h*WW + gw] : (unsigned short)0;
        }
    }
    // stage u16 half-row (uint4 copy, 672 quads)
    {
        const uint4* src = (const uint4*)(u16 + (size_t)h*ROWF + w0*CC);
        uint4* dst = (uint4*)lu16;
        #pragma unroll
        for (int j = 0; j < 3; ++j) {
            int idx = j*256 + tx;
            if (idx < HROWF/8) dst[idx] = src[idx];
        }
    }
    __syncthreads();

    int w = w0 + tx;
    int p = h*WW + w;

    // horizontal blur -> the ONLY per-thread register array
    float b[CC];
    #pragma unroll
    for (int c = 0; c < CC; ++c) {
        float a = 0.f;
        #pragma unroll
        for (int t = 0; t < 9; ++t) a += kk.k[t] * bf16_to_f(tile16[c*TSTRIDE + tx + 4 + t]);
        b[c] = a;
    }
    __syncthreads();          // tile reads done -> qlds region reusable

    // separable norm = s(h)*s(w)
    float sv = 0.f, swn = 0.f;
    #pragma unroll
    for (int t = 0; t < 9; ++t) {
        int hh = h + t - 4; if (hh >= 0 && hh < HH) sv  += kk.k[t];
        int wi = w + t - 4; if (wi >= 0 && wi < WW) swn += kk.k[t];
    }
    float invnorm = 1.f / (sv * swn);

    int idxv = sp_indices[iter];
    int lab  = spT[p];
    bool in1 = (lab == idxv), in2 = (lab == idxv + 1);
    bool incur = in1 | in2;
    float hw0 = hwg[0], hw1 = hwg[1];
    float attc = hw0 + hw1;                  // att for non-clique pixels

    // branch-free unrolled M-mix (constant Mg offsets -> scalar loads)
    float qmax = -1e30f;
    #pragma unroll
    for (int c = 0; c < CC; ++c) {
        float pw = 0.f;
        #pragma unroll
        for (int k = 0; k < CC; ++k) pw += Mg[c*CC + k] * b[k];
        float qv = bf16_to_f(lu16[tx*CC + c]) - pw*invnorm - attc;
        qlds[c*256 + tx] = qv;
        qmax = fmaxf(qmax, qv);
    }
    // rare clique fixup (~650 px total)
    if (incur) {
        qmax = -1e30f;
        for (int c = 0; c < CC; ++c) {
            float smv = smf[(size_t)c*HWSZ + p];
            float qm  = (smv == 0.f) ? 1.f : smv;
            float ft1 = in1 ? Bg[c]      / qm : 0.f;
            float ft2 = in2 ? Bg[CC + c] / qm : 0.f;
            float fta = ft1 + ft2;
            float att = lwg[c]*ft1 + hw0*(1.f - ft1) + lwg[CC + c]*fta + hw1*(1.f - fta);
            float qv = qlds[c*256 + tx] + attc - att;
            qlds[c*256 + tx] = qv;
            qmax = fmaxf(qmax, qv);
        }
    }

    if (!last) {
        // softmax: reuse b[] (dead after M-mix) -> qlds write-once/read-once
        float ssum = 0.f;
        #pragma unroll
        for (int c = 0; c < CC; ++c) {
            float e = expf(qlds[c*256 + tx] - qmax);
            b[c] = e; ssum += e;
        }
        float inv = 1.f / ssum;
        #pragma unroll
        for (int c = 0; c < CC; ++c)
            sm16[(size_t)c*HWSZ + p] = f_to_bf16(b[c] * inv);

        int idx2 = sp_indices[iter + 1];
        bool n1 = (lab == idx2), n2 = (lab == idx2 + 1);
        if (n1 | n2) {
            int mk = n1 ? 0 : 1;
            anyC = 1;
            atomicAdd(&acc[42 + mk], 1.f);
            for (int c = 0; c < CC; ++c) {
                float smv = b[c] * inv;
                smf[(size_t)c*HWSZ + p] = smv;
                atomicAdd(&acc[mk*21 + c], expf(smv));
            }
        }
        __syncthreads();
        if (anyC && tx < 44) atomicAdd(&redacc[tx], acc[tx]);
    } else {
        // q5 -> out HWC: gather float4s directly from qlds, transposed index.
        __syncthreads();
        float4* dst = (float4*)(outHWC + (size_t)h*ROWF + w0*CC);
        #pragma unroll
        for (int j = 0; j < 6; ++j) {
            int idx = j*256 + tx;
            if (idx < HROWF/4) {
                int e = idx * 4;              // e = pix*CC + c
                float4 o;
                o.x = qlds[(e       % CC)*256 + (e       / CC)];
                o.y = qlds[((e + 1) % CC)*256 + ((e + 1) / CC)];
                o.z = qlds[((e + 2) % CC)*256 + ((e + 2) / CC)];
                o.w = qlds[((e + 3) % CC)*256 + ((e + 3) / CC)];
                dst[idx] = o;
            }
        }
    }
}

extern "C" void kernel_launch(void* const* d_in, const int* in_sizes, int n_in,
                              void* d_out, int out_size, void* d_ws, size_t ws_size,
                              hipStream_t stream) {
    const float* unaries    = (const float*)d_in[0];
    // d_in[1] = rgb (unused by the reference)
    const int*   sp_map     = (const int*)d_in[2];
    const int*   sp_indices = (const int*)d_in[3];
    const float* skw        = (const float*)d_in[4];
    const float* bkw        = (const float*)d_in[5];
    const float* cm         = (const float*)d_in[6];
    const float* lw         = (const float*)d_in[7];
    const float* hwt        = (const float*)d_in[8];
    float* out = (float*)d_out;

    char* wsb = (char*)d_ws;
    unsigned short* sm16  = (unsigned short*)wsb;                // CHW bf16
    unsigned short* tmp16 = sm16 + CHW;                          // CHW bf16
    unsigned short* u16   = tmp16 + CHW;                         // CHW bf16
    float* smf  = (float*)(u16 + CHW);                           // CHW fp32 (sparse use)
    float* M    = smf + CHW;                                     // 441
    float* Bv   = M + CC*CC;                                     // 42 (+pad)
    float* redacc = Bv + 64;                                     // 44
    int*   spT  = (int*)(redacc + 64);                           // HWSZ ints

    // 9-tap normalized Gaussian, sigma=3 (fp32, matches reference)
    K9 kk;
    {
        float s = 0.f;
        for (int t = 0; t < 9; ++t) {
            float x = (float)(t - 4) / 3.0f;
            kk.k[t] = expf(-0.5f * x * x);
            s += kk.k[t];
        }
        for (int t = 0; t < 9; ++t) kk.k[t] /= s;
    }

    hipMemsetAsync(redacc, 0, 64*sizeof(float), stream);
    convert_u16_kernel<<<CHW/1024, 256, 0, stream>>>(unaries, u16);
    transpose_sp_kernel<<<HWSZ/256, 256, 0, stream>>>(sp_map, spT);
    precomp_M_kernel<<<2, 256, 0, stream>>>(skw, bkw, cm, M);
    init_sm_kernel<<<1024, 256, 0, stream>>>(unaries, sm16, smf, spT, sp_indices, redacc);

    for (int it = 0; it < NITERS; ++it) {
        finalize_kernel<<<1, 64, 0, stream>>>(redacc, Bv);            // B_it, re-zero
        vblur_kernel<<<CHW/2048, 256, 0, stream>>>(sm16, tmp16, kk);  // sm_it -> tmp
        int last = (it == NITERS - 1);
        final_kernel<<<1024, 256, 0, stream>>>(tmp16, sm16, smf, out, u16, spT,
                                               sp_indices, it, M, Bv, lw, hwt,
                                               kk, redacc, last);
    }
}